// Round 1
// baseline (12546.378 us; speedup 1.0000x reference)
//
#include <hip/hip_runtime.h>

// ---------------------------------------------------------------------------
// USFM ViT (BEiT-style) forward, MI355X gfx950.
// B=32, C=3, IMG=224, P=16, G=14, N=197, D=768, H=12, HD=64, FF=3072, L=12, NR=732
// Strategy: bf16 MFMA 16x16x32 GEMMs (128x128 tile, global_load_lds staging),
// fp32 residual stream + LN, fp32 VALU attention with K/V in LDS.
// ---------------------------------------------------------------------------

#define BATCH 32
#define NTOK 197
#define DMODEL 768
#define NHEAD 12
#define HDIM 64
#define FFDIM 3072
#define NLAYER 12
#define NRR 732
#define MROWS (BATCH * NTOK)   // 6304
#define MPAD 6400              // padded to multiple of 128

typedef __attribute__((ext_vector_type(8))) short bf16x8_t;
typedef __attribute__((ext_vector_type(4))) float f32x4_t;

__device__ __forceinline__ unsigned short f2bf_rn(float f) {
  unsigned u = __float_as_uint(f);
  unsigned r = (u + 0x7FFFu + ((u >> 16) & 1u)) >> 16;
  return (unsigned short)r;
}
__device__ __forceinline__ float bf2f(unsigned short u) {
  return __uint_as_float(((unsigned)u) << 16);
}

__device__ __forceinline__ void gld16(const unsigned short* g, unsigned short* l) {
  __builtin_amdgcn_global_load_lds(
      (const __attribute__((address_space(1))) unsigned int*)g,
      (__attribute__((address_space(3))) unsigned int*)l, 16, 0, 0);
}

// ---------------------------------------------------------------------------
// fp32 -> bf16 converters
// ---------------------------------------------------------------------------
__global__ void cvt4(const float4* __restrict__ s, ushort4* __restrict__ d, int n4) {
  int i = blockIdx.x * 256 + threadIdx.x;
  if (i >= n4) return;
  float4 v = s[i];
  ushort4 r;
  r.x = f2bf_rn(v.x); r.y = f2bf_rn(v.y); r.z = f2bf_rn(v.z); r.w = f2bf_rn(v.w);
  d[i] = r;
}

// convert one layer's 4 weight tensors into a contiguous bf16 buffer
__global__ void cvt_layer(const float4* __restrict__ qw, const float4* __restrict__ pw,
                          const float4* __restrict__ f1, const float4* __restrict__ f2,
                          ushort4* __restrict__ dst) {
  const int n_q = 2304 * 768 / 4;   // 442368
  const int n_p = 768 * 768 / 4;    // 147456
  const int n_1 = 3072 * 768 / 4;   // 589824
  int i = blockIdx.x * 256 + threadIdx.x;
  float4 v;
  if (i < n_q) v = qw[i];
  else if (i < n_q + n_p) v = pw[i - n_q];
  else if (i < n_q + n_p + n_1) v = f1[i - n_q - n_p];
  else if (i < n_q + n_p + 2 * n_1) v = f2[i - n_q - n_p - n_1];
  else return;
  ushort4 r;
  r.x = f2bf_rn(v.x); r.y = f2bf_rn(v.y); r.z = f2bf_rn(v.z); r.w = f2bf_rn(v.w);
  dst[i] = r;
}

// ---------------------------------------------------------------------------
// patch unfold: x [B,3,224,224] -> xp bf16 [MPAD,768], row b*197+1+p
// ---------------------------------------------------------------------------
__global__ void build_xp(const float* __restrict__ x, unsigned short* __restrict__ xp) {
  int idx = blockIdx.x * 256 + threadIdx.x;   // over 6272*768
  if (idx >= 6272 * 768) return;
  int r = idx / 768, c = idx - r * 768;
  int b = r / 196, p = r - b * 196;
  int gy = p / 14, gx = p - gy * 14;
  int ch = c >> 8, rem = c & 255, py = rem >> 4, px = rem & 15;
  float v = x[(((size_t)b * 3 + ch) * 224 + gy * 16 + py) * 224 + gx * 16 + px];
  xp[(size_t)(b * 197 + 1 + p) * 768 + c] = f2bf_rn(v);
}

__global__ void fill_cls(const float* __restrict__ cls, float* __restrict__ tok) {
  int idx = blockIdx.x * 256 + threadIdx.x;   // 32*768
  int b = idx / 768, d = idx - b * 768;
  tok[(size_t)(b * 197) * 768 + d] = cls[d];
}

// ---------------------------------------------------------------------------
// LayerNorm rows: fp32 in -> bf16 out  (one block per row)
// ---------------------------------------------------------------------------
__global__ __launch_bounds__(256) void ln_rows(const float* __restrict__ x,
                                               unsigned short* __restrict__ y,
                                               const float* __restrict__ g,
                                               const float* __restrict__ b) {
  int row = blockIdx.x;
  const float* xr = x + (size_t)row * 768;
  int t = threadIdx.x;
  float v0 = xr[t], v1 = xr[t + 256], v2 = xr[t + 512];
  float s = v0 + v1 + v2;
  float q = v0 * v0 + v1 * v1 + v2 * v2;
  for (int off = 32; off; off >>= 1) { s += __shfl_xor(s, off); q += __shfl_xor(q, off); }
  __shared__ float rs[4], rq[4];
  int wave = t >> 6;
  if ((t & 63) == 0) { rs[wave] = s; rq[wave] = q; }
  __syncthreads();
  s = rs[0] + rs[1] + rs[2] + rs[3];
  q = rq[0] + rq[1] + rq[2] + rq[3];
  float mean = s * (1.f / 768.f);
  float var = q * (1.f / 768.f) - mean * mean;
  float rstd = rsqrtf(var + 1e-5f);
  unsigned short* yr = y + (size_t)row * 768;
  yr[t]       = f2bf_rn((v0 - mean) * rstd * g[t]       + b[t]);
  yr[t + 256] = f2bf_rn((v1 - mean) * rstd * g[t + 256] + b[t + 256]);
  yr[t + 512] = f2bf_rn((v2 - mean) * rstd * g[t + 512] + b[t + 512]);
}

// ---------------------------------------------------------------------------
// MFMA GEMM: out = A[M,K] @ Bw[N,K]^T, bf16 inputs, fp32 accum.
// 128x128 tile, BK=32, 256 threads (4 waves, each 64x64 with 4x4 16x16 accs).
// MODE 0: Cf = acc + bias                (patch embed, fp32 out)
// MODE 1: Cb = bf16((acc+qkvbias)*scale) (qkv; q cols *0.125)
// MODE 2: Cf += gamma*(acc + bias)       (residual update, fp32 in/out)
// MODE 3: Cb = bf16(gelu(acc + bias))    (fc1)
// ---------------------------------------------------------------------------
template <int MODE>
__global__ __launch_bounds__(256, 2) void gemm128(
    const unsigned short* __restrict__ A, const unsigned short* __restrict__ Bw,
    float* __restrict__ Cf, unsigned short* __restrict__ Cb,
    const float* __restrict__ bias, const float* __restrict__ bias2,
    const float* __restrict__ gamma, int K, int N) {
  __shared__ __align__(16) unsigned short As[128 * 32];
  __shared__ __align__(16) unsigned short Bs[128 * 32];
  const int tid = threadIdx.x;
  const int wave = tid >> 6, lane = tid & 63;
  const int m0 = blockIdx.y * 128, n0 = blockIdx.x * 128;
  const int wm = (wave & 1) * 64, wn = (wave >> 1) * 64;
  f32x4_t acc[4][4] = {};
  // staging: unit = 16 rows x 32 cols (1KB); lane i -> row i/4, col (i%4)*8
  const int srow = lane >> 2;
  const int scol = (lane & 3) * 8;
  const unsigned short* Abase = A + (size_t)(m0 + srow) * K + scol;
  const unsigned short* Bbase = Bw + (size_t)(n0 + srow) * K + scol;
  const int fr = lane & 15, fq = (lane >> 4) * 8;
  for (int k0 = 0; k0 < K; k0 += 32) {
    __syncthreads();
#pragma unroll
    for (int u0 = 0; u0 < 2; ++u0) {
      int u = wave + u0 * 4;
      gld16(Abase + (size_t)(u * 16) * K + k0, As + u * 512);
      gld16(Bbase + (size_t)(u * 16) * K + k0, Bs + u * 512);
    }
    __syncthreads();
    bf16x8_t af[4], bfr[4];
#pragma unroll
    for (int i = 0; i < 4; ++i) {
      af[i]  = *(const bf16x8_t*)(As + (wm + i * 16 + fr) * 32 + fq);
      bfr[i] = *(const bf16x8_t*)(Bs + (wn + i * 16 + fr) * 32 + fq);
    }
#pragma unroll
    for (int i = 0; i < 4; ++i)
#pragma unroll
      for (int j = 0; j < 4; ++j)
        acc[i][j] = __builtin_amdgcn_mfma_f32_16x16x32_bf16(af[i], bfr[j], acc[i][j], 0, 0, 0);
  }
  // epilogue: C/D layout col=lane&15, row=(lane>>4)*4+reg (m89-verified)
  const int er = (lane >> 4) * 4;
  const int ec = lane & 15;
#pragma unroll
  for (int i = 0; i < 4; ++i) {
#pragma unroll
    for (int j = 0; j < 4; ++j) {
#pragma unroll
      for (int r = 0; r < 4; ++r) {
        int row = m0 + wm + i * 16 + er + r;
        int col = n0 + wn + j * 16 + ec;
        float v = acc[i][j][r];
        size_t idx = (size_t)row * N + col;
        if constexpr (MODE == 0) {
          Cf[idx] = v + bias[col];
        } else if constexpr (MODE == 1) {
          float bv = (col < 768) ? bias[col] : (col >= 1536 ? bias2[col - 1536] : 0.f);
          v += bv;
          if (col < 768) v *= 0.125f;  // SCALE = 64^-0.5
          Cb[idx] = f2bf_rn(v);
        } else if constexpr (MODE == 2) {
          Cf[idx] = Cf[idx] + gamma[col] * (v + bias[col]);
        } else {
          float tt = v + bias[col];
          float gv = 0.5f * tt * (1.f + erff(tt * 0.70710678118654752f));
          Cb[idx] = f2bf_rn(gv);
        }
      }
    }
  }
}

// ---------------------------------------------------------------------------
// attention: one block per (b,h). qkv bf16 [MPAD,2304] (q pre-scaled).
// K,V staged in LDS (stride 66 to avoid bank conflicts). fp32 softmax.
// ---------------------------------------------------------------------------
__global__ __launch_bounds__(256) void attn_kern(
    const unsigned short* __restrict__ qkv, const float* __restrict__ rt,
    const int* __restrict__ ridx, unsigned short* __restrict__ o) {
  const int bh = blockIdx.x;
  const int b = bh / 12, h = bh - b * 12;
  __shared__ __align__(16) unsigned short kls[197 * 66];
  __shared__ __align__(16) unsigned short vls[197 * 66];
  __shared__ float qbuf[64];
  __shared__ float sc[256];
  __shared__ float red[8];
  __shared__ float opart[256];
  const int t = threadIdx.x;
  const int lane = t & 63, wave = t >> 6;
  const size_t rowbase = (size_t)(b * 197) * 2304 + h * 64;
  for (int idx = t; idx < 197 * 64; idx += 256) {
    int j = idx >> 6, d = idx & 63;
    size_t src = rowbase + (size_t)j * 2304 + d;
    kls[j * 66 + d] = qkv[src + 768];
    vls[j * 66 + d] = qkv[src + 1536];
  }
  __syncthreads();
  for (int i = 0; i < 197; ++i) {
    if (t < 64) qbuf[t] = bf2f(qkv[rowbase + (size_t)i * 2304 + t]);
    __syncthreads();
    float s = -1e30f;
    if (t < 197) {
      float a = 0.f;
      const ushort2* kp = (const ushort2*)(kls + t * 66);
      const float2* qp = (const float2*)qbuf;
#pragma unroll 8
      for (int dd = 0; dd < 32; ++dd) {
        ushort2 kk = kp[dd];
        float2 qq = qp[dd];
        a += qq.x * bf2f(kk.x) + qq.y * bf2f(kk.y);
      }
      a += rt[(size_t)ridx[i * 197 + t] * 12 + h];
      s = a;
    }
    float m = s;
    for (int off = 32; off; off >>= 1) m = fmaxf(m, __shfl_xor(m, off));
    if (lane == 0) red[wave] = m;
    __syncthreads();
    m = fmaxf(fmaxf(red[0], red[1]), fmaxf(red[2], red[3]));
    float p = (t < 197) ? __expf(s - m) : 0.f;
    sc[t] = p;
    float lsum = p;
    for (int off = 32; off; off >>= 1) lsum += __shfl_xor(lsum, off);
    if (lane == 0) red[4 + wave] = lsum;
    __syncthreads();
    lsum = red[4] + red[5] + red[6] + red[7];
    const int d = t & 63, g = t >> 6;
    float pa = 0.f;
    for (int j = g; j < 197; j += 4)
      pa += sc[j] * bf2f(vls[j * 66 + d]);
    opart[t] = pa;
    __syncthreads();
    if (t < 64) {
      float ov = (opart[t] + opart[64 + t] + opart[128 + t] + opart[192 + t]) / lsum;
      o[(size_t)(b * 197 + i) * 768 + h * 64 + t] = f2bf_rn(ov);
    }
    __syncthreads();
  }
}

// ---------------------------------------------------------------------------
// final: mean over patch tokens + fc_norm -> out [32,768] fp32
// ---------------------------------------------------------------------------
__global__ __launch_bounds__(256) void pool_ln(const float* __restrict__ tok,
                                               const float* __restrict__ g,
                                               const float* __restrict__ bb,
                                               float* __restrict__ out) {
  int b = blockIdx.x;
  __shared__ float pool[768];
  int t = threadIdx.x;
  for (int c = t; c < 768; c += 256) {
    float s = 0.f;
    const float* p = tok + (size_t)(b * 197 + 1) * 768 + c;
    for (int i = 0; i < 196; ++i) s += p[(size_t)i * 768];
    pool[c] = s * (1.f / 196.f);
  }
  __syncthreads();
  float s = 0.f, q = 0.f;
  for (int c = t; c < 768; c += 256) { float v = pool[c]; s += v; q += v * v; }
  for (int off = 32; off; off >>= 1) { s += __shfl_xor(s, off); q += __shfl_xor(q, off); }
  __shared__ float rs[4], rq[4];
  if ((t & 63) == 0) { rs[t >> 6] = s; rq[t >> 6] = q; }
  __syncthreads();
  s = rs[0] + rs[1] + rs[2] + rs[3];
  q = rq[0] + rq[1] + rq[2] + rq[3];
  float mean = s * (1.f / 768.f);
  float var = q * (1.f / 768.f) - mean * mean;
  float rstd = rsqrtf(var + 1e-5f);
  for (int c = t; c < 768; c += 256)
    out[(size_t)b * 768 + c] = (pool[c] - mean) * rstd * g[c] + bb[c];
}

// ---------------------------------------------------------------------------
extern "C" void kernel_launch(void* const* d_in, const int* in_sizes, int n_in,
                              void* d_out, int out_size, void* d_ws, size_t ws_size,
                              hipStream_t stream) {
  const float* x         = (const float*)d_in[0];
  const float* patch_w   = (const float*)d_in[1];
  const float* patch_b   = (const float*)d_in[2];
  const float* cls_tok   = (const float*)d_in[3];
  const float* ln1_g     = (const float*)d_in[4];
  const float* ln1_b     = (const float*)d_in[5];
  const float* qkv_w     = (const float*)d_in[6];
  const float* q_bias    = (const float*)d_in[7];
  const float* v_bias    = (const float*)d_in[8];
  const float* rel_table = (const float*)d_in[9];
  const float* proj_w    = (const float*)d_in[10];
  const float* proj_b    = (const float*)d_in[11];
  const float* gamma1    = (const float*)d_in[12];
  const float* ln2_g     = (const float*)d_in[13];
  const float* ln2_b     = (const float*)d_in[14];
  const float* fc1_w     = (const float*)d_in[15];
  const float* fc1_b     = (const float*)d_in[16];
  const float* fc2_w     = (const float*)d_in[17];
  const float* fc2_b     = (const float*)d_in[18];
  const float* gamma2    = (const float*)d_in[19];
  const float* fcn_g     = (const float*)d_in[20];
  const float* fcn_b     = (const float*)d_in[21];
  const int* rel_index   = (const int*)d_in[22];
  float* out = (float*)d_out;

  char* ws = (char*)d_ws;
  size_t off = 0;
  auto take = [&](size_t bytes) {
    char* p = ws + off;
    off += (bytes + 255) & ~(size_t)255;
    return p;
  };
  // per-layer bf16 weights: qkv | proj | fc1 | fc2 (contiguous)
  unsigned short* wl     = (unsigned short*)take((size_t)8257536 * 2);
  unsigned short* pwb    = (unsigned short*)take((size_t)589824 * 2);
  float*          tokf   = (float*)take((size_t)MPAD * 768 * 4);
  unsigned short* hb     = (unsigned short*)take((size_t)MPAD * 768 * 2);   // aliased as attn-out
  unsigned short* qkvb   = (unsigned short*)take((size_t)MPAD * 2304 * 2);
  unsigned short* ffb    = (unsigned short*)take((size_t)MPAD * 3072 * 2);  // aliased as xp
  unsigned short* xp = ffb;
  unsigned short* ob = hb;
  unsigned short* wl_qkv = wl;
  unsigned short* wl_proj = wl + (size_t)2304 * 768;
  unsigned short* wl_fc1 = wl_proj + (size_t)768 * 768;
  unsigned short* wl_fc2 = wl_fc1 + (size_t)3072 * 768;

  // patch embed
  cvt4<<<576, 256, 0, stream>>>((const float4*)patch_w, (ushort4*)pwb, 147456);
  build_xp<<<18816, 256, 0, stream>>>(x, xp);
  gemm128<0><<<dim3(6, 50), 256, 0, stream>>>(xp, pwb, tokf, nullptr, patch_b,
                                              nullptr, nullptr, 768, 768);
  fill_cls<<<96, 256, 0, stream>>>(cls_tok, tokf);

  for (int l = 0; l < NLAYER; ++l) {
    cvt_layer<<<6912, 256, 0, stream>>>(
        (const float4*)(qkv_w + (size_t)l * 2304 * 768),
        (const float4*)(proj_w + (size_t)l * 768 * 768),
        (const float4*)(fc1_w + (size_t)l * 3072 * 768),
        (const float4*)(fc2_w + (size_t)l * 768 * 3072), (ushort4*)wl);
    ln_rows<<<MROWS, 256, 0, stream>>>(tokf, hb, ln1_g + l * 768, ln1_b + l * 768);
    gemm128<1><<<dim3(18, 50), 256, 0, stream>>>(hb, wl_qkv, nullptr, qkvb,
                                                 q_bias + l * 768, v_bias + l * 768,
                                                 nullptr, 768, 2304);
    attn_kern<<<384, 256, 0, stream>>>(qkvb, rel_table + (size_t)l * NRR * 12,
                                       rel_index, ob);
    gemm128<2><<<dim3(6, 50), 256, 0, stream>>>(ob, wl_proj, tokf, nullptr,
                                                proj_b + l * 768, nullptr,
                                                gamma1 + l * 768, 768, 768);
    ln_rows<<<MROWS, 256, 0, stream>>>(tokf, hb, ln2_g + l * 768, ln2_b + l * 768);
    gemm128<3><<<dim3(24, 50), 256, 0, stream>>>(hb, wl_fc1, nullptr, ffb,
                                                 fc1_b + l * 3072, nullptr, nullptr,
                                                 768, 3072);
    gemm128<2><<<dim3(6, 50), 256, 0, stream>>>(ffb, wl_fc2, tokf, nullptr,
                                                fc2_b + l * 768, nullptr,
                                                gamma2 + l * 768, 3072, 768);
  }
  pool_ln<<<32, 256, 0, stream>>>(tokf, fcn_g, fcn_b, out);
}

// Round 2
// 3695.918 us; speedup vs baseline: 3.3947x; 3.3947x over previous
//
#include <hip/hip_runtime.h>

// ---------------------------------------------------------------------------
// USFM ViT (BEiT-style) forward, MI355X gfx950.
// B=32, C=3, IMG=224, P=16, G=14, N=197, D=768, H=12, HD=64, FF=3072, L=12, NR=732
// bf16 MFMA GEMMs (128x128 tile) + MFMA flash-style attention.
// ---------------------------------------------------------------------------

#define BATCH 32
#define NTOK 197
#define NLAYER 12
#define NRR 732
#define MROWS (BATCH * NTOK)   // 6304
#define MPAD 6400              // padded to multiple of 128

#define NKV 224                // padded kv length (14 tiles of 16)
#define QT_N 13                // q tiles (208 rows >= 197)
#define VSTR 232               // Vt LDS row stride (shorts)
#define PSTR 232               // P  LDS row stride (shorts)
#define RPB_PER_LH (QT_N * 14 * 4 * 16 * 4)   // 46592
#define RPB_PER_L (RPB_PER_LH * 12)           // 559104

typedef __attribute__((ext_vector_type(8))) short bf16x8_t;
typedef __attribute__((ext_vector_type(4))) float f32x4_t;

__device__ __forceinline__ unsigned short f2bf_rn(float f) {
  unsigned u = __float_as_uint(f);
  unsigned r = (u + 0x7FFFu + ((u >> 16) & 1u)) >> 16;
  return (unsigned short)r;
}
__device__ __forceinline__ float bf2f(unsigned short u) {
  return __uint_as_float(((unsigned)u) << 16);
}

__device__ __forceinline__ void gld16(const unsigned short* g, unsigned short* l) {
  __builtin_amdgcn_global_load_lds(
      (const __attribute__((address_space(1))) unsigned int*)g,
      (__attribute__((address_space(3))) unsigned int*)l, 16, 0, 0);
}

// ---------------------------------------------------------------------------
// fp32 -> bf16 converters
// ---------------------------------------------------------------------------
__global__ void cvt4(const float4* __restrict__ s, ushort4* __restrict__ d, int n4) {
  int i = blockIdx.x * 256 + threadIdx.x;
  if (i >= n4) return;
  float4 v = s[i];
  ushort4 r;
  r.x = f2bf_rn(v.x); r.y = f2bf_rn(v.y); r.z = f2bf_rn(v.z); r.w = f2bf_rn(v.w);
  d[i] = r;
}

__global__ void cvt_layer(const float4* __restrict__ qw, const float4* __restrict__ pw,
                          const float4* __restrict__ f1, const float4* __restrict__ f2,
                          ushort4* __restrict__ dst) {
  const int n_q = 2304 * 768 / 4;
  const int n_p = 768 * 768 / 4;
  const int n_1 = 3072 * 768 / 4;
  int i = blockIdx.x * 256 + threadIdx.x;
  float4 v;
  if (i < n_q) v = qw[i];
  else if (i < n_q + n_p) v = pw[i - n_q];
  else if (i < n_q + n_p + n_1) v = f1[i - n_q - n_p];
  else if (i < n_q + n_p + 2 * n_1) v = f2[i - n_q - n_p - n_1];
  else return;
  ushort4 r;
  r.x = f2bf_rn(v.x); r.y = f2bf_rn(v.y); r.z = f2bf_rn(v.z); r.w = f2bf_rn(v.w);
  dst[i] = r;
}

// ---------------------------------------------------------------------------
// rel-pos bias, pre-expanded to MFMA fragment order:
// rpb[l][h][qt][jt][fq][fr][r]  (bf16), mask (row/col >= 197) baked in as -3e4
// ---------------------------------------------------------------------------
__global__ void build_rpb(const float* __restrict__ rt, const int* __restrict__ ridx,
                          unsigned short* __restrict__ dst) {
  int idx = blockIdx.x * 256 + threadIdx.x;
  if (idx >= RPB_PER_L * NLAYER) return;
  int r = idx & 3;
  int fr = (idx >> 2) & 15;
  int fq = (idx >> 6) & 3;
  int t2 = idx >> 8;
  int jt = t2 % 14; t2 /= 14;
  int qt = t2 % QT_N; t2 /= QT_N;
  int h = t2 % 12;
  int l = t2 / 12;
  int row = qt * 16 + fq * 4 + r;
  int col = jt * 16 + fr;
  float v = -30000.f;
  if (row < 197 && col < 197)
    v = rt[((size_t)l * NRR + ridx[row * 197 + col]) * 12 + h];
  dst[idx] = f2bf_rn(v);
}

// ---------------------------------------------------------------------------
// patch unfold: x [B,3,224,224] -> xp bf16 [MPAD,768], row b*197+1+p
// ---------------------------------------------------------------------------
__global__ void build_xp(const float* __restrict__ x, unsigned short* __restrict__ xp) {
  int idx = blockIdx.x * 256 + threadIdx.x;
  if (idx >= 6272 * 768) return;
  int r = idx / 768, c = idx - r * 768;
  int b = r / 196, p = r - b * 196;
  int gy = p / 14, gx = p - gy * 14;
  int ch = c >> 8, rem = c & 255, py = rem >> 4, px = rem & 15;
  float v = x[(((size_t)b * 3 + ch) * 224 + gy * 16 + py) * 224 + gx * 16 + px];
  xp[(size_t)(b * 197 + 1 + p) * 768 + c] = f2bf_rn(v);
}

__global__ void fill_cls(const float* __restrict__ cls, float* __restrict__ tok) {
  int idx = blockIdx.x * 256 + threadIdx.x;
  int b = idx / 768, d = idx - b * 768;
  tok[(size_t)(b * 197) * 768 + d] = cls[d];
}

// ---------------------------------------------------------------------------
// LayerNorm rows: fp32 in -> bf16 out  (one block per row)
// ---------------------------------------------------------------------------
__global__ __launch_bounds__(256) void ln_rows(const float* __restrict__ x,
                                               unsigned short* __restrict__ y,
                                               const float* __restrict__ g,
                                               const float* __restrict__ b) {
  int row = blockIdx.x;
  const float* xr = x + (size_t)row * 768;
  int t = threadIdx.x;
  float v0 = xr[t], v1 = xr[t + 256], v2 = xr[t + 512];
  float s = v0 + v1 + v2;
  float q = v0 * v0 + v1 * v1 + v2 * v2;
  for (int off = 32; off; off >>= 1) { s += __shfl_xor(s, off); q += __shfl_xor(q, off); }
  __shared__ float rs[4], rq[4];
  int wave = t >> 6;
  if ((t & 63) == 0) { rs[wave] = s; rq[wave] = q; }
  __syncthreads();
  s = rs[0] + rs[1] + rs[2] + rs[3];
  q = rq[0] + rq[1] + rq[2] + rq[3];
  float mean = s * (1.f / 768.f);
  float var = q * (1.f / 768.f) - mean * mean;
  float rstd = rsqrtf(var + 1e-5f);
  unsigned short* yr = y + (size_t)row * 768;
  yr[t]       = f2bf_rn((v0 - mean) * rstd * g[t]       + b[t]);
  yr[t + 256] = f2bf_rn((v1 - mean) * rstd * g[t + 256] + b[t + 256]);
  yr[t + 512] = f2bf_rn((v2 - mean) * rstd * g[t + 512] + b[t + 512]);
}

// ---------------------------------------------------------------------------
// MFMA GEMM: out = A[M,K] @ Bw[N,K]^T, bf16 in, fp32 accum. 128x128 tile.
// MODE 0: Cf = acc + bias; MODE 1: qkv epilogue; MODE 2: residual; MODE 3: gelu
// ---------------------------------------------------------------------------
template <int MODE>
__global__ __launch_bounds__(256, 2) void gemm128(
    const unsigned short* __restrict__ A, const unsigned short* __restrict__ Bw,
    float* __restrict__ Cf, unsigned short* __restrict__ Cb,
    const float* __restrict__ bias, const float* __restrict__ bias2,
    const float* __restrict__ gamma, int K, int N) {
  __shared__ __align__(16) unsigned short As[128 * 32];
  __shared__ __align__(16) unsigned short Bs[128 * 32];
  const int tid = threadIdx.x;
  const int wave = tid >> 6, lane = tid & 63;
  const int m0 = blockIdx.y * 128, n0 = blockIdx.x * 128;
  const int wm = (wave & 1) * 64, wn = (wave >> 1) * 64;
  f32x4_t acc[4][4] = {};
  const int srow = lane >> 2;
  const int scol = (lane & 3) * 8;
  const unsigned short* Abase = A + (size_t)(m0 + srow) * K + scol;
  const unsigned short* Bbase = Bw + (size_t)(n0 + srow) * K + scol;
  const int fr = lane & 15, fq = (lane >> 4) * 8;
  for (int k0 = 0; k0 < K; k0 += 32) {
    __syncthreads();
#pragma unroll
    for (int u0 = 0; u0 < 2; ++u0) {
      int u = wave + u0 * 4;
      gld16(Abase + (size_t)(u * 16) * K + k0, As + u * 512);
      gld16(Bbase + (size_t)(u * 16) * K + k0, Bs + u * 512);
    }
    __syncthreads();
    bf16x8_t af[4], bfr[4];
#pragma unroll
    for (int i = 0; i < 4; ++i) {
      af[i]  = *(const bf16x8_t*)(As + (wm + i * 16 + fr) * 32 + fq);
      bfr[i] = *(const bf16x8_t*)(Bs + (wn + i * 16 + fr) * 32 + fq);
    }
#pragma unroll
    for (int i = 0; i < 4; ++i)
#pragma unroll
      for (int j = 0; j < 4; ++j)
        acc[i][j] = __builtin_amdgcn_mfma_f32_16x16x32_bf16(af[i], bfr[j], acc[i][j], 0, 0, 0);
  }
  const int er = (lane >> 4) * 4;
  const int ec = lane & 15;
#pragma unroll
  for (int i = 0; i < 4; ++i) {
#pragma unroll
    for (int j = 0; j < 4; ++j) {
#pragma unroll
      for (int r = 0; r < 4; ++r) {
        int row = m0 + wm + i * 16 + er + r;
        int col = n0 + wn + j * 16 + ec;
        float v = acc[i][j][r];
        size_t idx = (size_t)row * N + col;
        if constexpr (MODE == 0) {
          Cf[idx] = v + bias[col];
        } else if constexpr (MODE == 1) {
          float bv = (col < 768) ? bias[col] : (col >= 1536 ? bias2[col - 1536] : 0.f);
          v += bv;
          if (col < 768) v *= 0.125f;  // SCALE = 64^-0.5
          Cb[idx] = f2bf_rn(v);
        } else if constexpr (MODE == 2) {
          Cf[idx] = Cf[idx] + gamma[col] * (v + bias[col]);
        } else {
          float tt = v + bias[col];
          float gv = 0.5f * tt * (1.f + erff(tt * 0.70710678118654752f));
          Cb[idx] = f2bf_rn(gv);
        }
      }
    }
  }
}

// ---------------------------------------------------------------------------
// MFMA attention: one block per (b,h), 4 waves, q-tiles striped over waves.
// Q/K fragments straight from global (L1/L2-hot); V transposed in LDS;
// P transposed C->A layout through per-wave LDS buffer. One barrier total.
// ---------------------------------------------------------------------------
__global__ __launch_bounds__(256) void attn_mfma(
    const unsigned short* __restrict__ qkv,   // [MPAD][2304], q pre-scaled
    const unsigned short* __restrict__ rpb,   // this layer: [12][RPB_PER_LH]
    unsigned short* __restrict__ o) {         // [MPAD][768]
  const int bh = blockIdx.x;
  const int b = bh / 12, h = bh - b * 12;
  __shared__ __align__(16) unsigned short Vt[64 * VSTR];       // 29.0 KB
  __shared__ __align__(16) unsigned short Pls[4][16 * PSTR];   // 29.0 KB
  const int t = threadIdx.x;
  const int wave = t >> 6, lane = t & 63;
  const int fr = lane & 15, fq = lane >> 4;
  const size_t qbase = (size_t)(b * 197) * 2304 + h * 64;
  const unsigned short* rph = rpb + (size_t)h * RPB_PER_LH;

  // stage V transposed: V[j][d] -> Vt[d][j]
  for (int idx = t; idx < NKV * 16; idx += 256) {
    int j = idx >> 4, d0 = (idx & 15) * 4;
    ushort4 v = *(const ushort4*)(qkv + qbase + 1536 + (size_t)j * 2304 + d0);
    Vt[(d0 + 0) * VSTR + j] = v.x;
    Vt[(d0 + 1) * VSTR + j] = v.y;
    Vt[(d0 + 2) * VSTR + j] = v.z;
    Vt[(d0 + 3) * VSTR + j] = v.w;
  }
  __syncthreads();

  unsigned short* P = &Pls[wave][0];
  for (int qt = wave; qt < QT_N; qt += 4) {
    // Q A-fragments (2 k-steps of 32)
    const unsigned short* qrow = qkv + qbase + (size_t)(qt * 16 + fr) * 2304 + fq * 8;
    bf16x8_t qa0 = *(const bf16x8_t*)(qrow);
    bf16x8_t qa1 = *(const bf16x8_t*)(qrow + 32);
    // S = Q.K^T + bias, 14 k-tiles held in registers (C-layout)
    f32x4_t S[14];
#pragma unroll
    for (int jt = 0; jt < 14; ++jt) {
      const unsigned short* krow = qkv + qbase + 768 + (size_t)(jt * 16 + fr) * 2304 + fq * 8;
      bf16x8_t kb0 = *(const bf16x8_t*)(krow);
      bf16x8_t kb1 = *(const bf16x8_t*)(krow + 32);
      f32x4_t s = {};
      s = __builtin_amdgcn_mfma_f32_16x16x32_bf16(qa0, kb0, s, 0, 0, 0);
      s = __builtin_amdgcn_mfma_f32_16x16x32_bf16(qa1, kb1, s, 0, 0, 0);
      ushort4 rb = *(const ushort4*)(rph + ((size_t)(qt * 14 + jt) * 4 + fq) * 64 + fr * 4);
      s[0] += bf2f(rb.x); s[1] += bf2f(rb.y); s[2] += bf2f(rb.z); s[3] += bf2f(rb.w);
      S[jt] = s;
    }
    // softmax over 224 cols (mask baked into rpb)
    float mx[4], sum[4];
#pragma unroll
    for (int r = 0; r < 4; ++r) mx[r] = S[0][r];
#pragma unroll
    for (int jt = 1; jt < 14; ++jt)
#pragma unroll
      for (int r = 0; r < 4; ++r) mx[r] = fmaxf(mx[r], S[jt][r]);
#pragma unroll
    for (int r = 0; r < 4; ++r) {
      for (int off = 1; off < 16; off <<= 1) mx[r] = fmaxf(mx[r], __shfl_xor(mx[r], off));
      sum[r] = 0.f;
    }
#pragma unroll
    for (int jt = 0; jt < 14; ++jt) {
#pragma unroll
      for (int r = 0; r < 4; ++r) {
        float p = __expf(S[jt][r] - mx[r]);
        sum[r] += p;
        P[(fq * 4 + r) * PSTR + jt * 16 + fr] = f2bf_rn(p);
      }
    }
    float rinv[4];
#pragma unroll
    for (int r = 0; r < 4; ++r) {
      for (int off = 1; off < 16; off <<= 1) sum[r] += __shfl_xor(sum[r], off);
      rinv[r] = 1.f / sum[r];
    }
    // PV: A = P (A-layout via LDS), B = Vt rows
    bf16x8_t pa[7];
#pragma unroll
    for (int ks = 0; ks < 7; ++ks)
      pa[ks] = *(const bf16x8_t*)(P + fr * PSTR + ks * 32 + fq * 8);
#pragma unroll
    for (int nt = 0; nt < 4; ++nt) {
      f32x4_t O = {};
#pragma unroll
      for (int ks = 0; ks < 7; ++ks) {
        bf16x8_t vb = *(const bf16x8_t*)(Vt + (nt * 16 + fr) * VSTR + ks * 32 + fq * 8);
        O = __builtin_amdgcn_mfma_f32_16x16x32_bf16(pa[ks], vb, O, 0, 0, 0);
      }
#pragma unroll
      for (int r = 0; r < 4; ++r) {
        int row = qt * 16 + fq * 4 + r;
        if (row < 197)
          o[(size_t)(b * 197 + row) * 768 + h * 64 + nt * 16 + fr] = f2bf_rn(O[r] * rinv[r]);
      }
    }
  }
}

// ---------------------------------------------------------------------------
// final: mean over patch tokens + fc_norm -> out [32,768] fp32
// ---------------------------------------------------------------------------
__global__ __launch_bounds__(256) void pool_ln(const float* __restrict__ tok,
                                               const float* __restrict__ g,
                                               const float* __restrict__ bb,
                                               float* __restrict__ out) {
  int b = blockIdx.x;
  __shared__ float pool[768];
  int t = threadIdx.x;
  for (int c = t; c < 768; c += 256) {
    float s = 0.f;
    const float* p = tok + (size_t)(b * 197 + 1) * 768 + c;
    for (int i = 0; i < 196; ++i) s += p[(size_t)i * 768];
    pool[c] = s * (1.f / 196.f);
  }
  __syncthreads();
  float s = 0.f, q = 0.f;
  for (int c = t; c < 768; c += 256) { float v = pool[c]; s += v; q += v * v; }
  for (int off = 32; off; off >>= 1) { s += __shfl_xor(s, off); q += __shfl_xor(q, off); }
  __shared__ float rs[4], rq[4];
  if ((t & 63) == 0) { rs[t >> 6] = s; rq[t >> 6] = q; }
  __syncthreads();
  s = rs[0] + rs[1] + rs[2] + rs[3];
  q = rq[0] + rq[1] + rq[2] + rq[3];
  float mean = s * (1.f / 768.f);
  float var = q * (1.f / 768.f) - mean * mean;
  float rstd = rsqrtf(var + 1e-5f);
  for (int c = t; c < 768; c += 256)
    out[(size_t)b * 768 + c] = (pool[c] - mean) * rstd * g[c] + bb[c];
}

// ---------------------------------------------------------------------------
extern "C" void kernel_launch(void* const* d_in, const int* in_sizes, int n_in,
                              void* d_out, int out_size, void* d_ws, size_t ws_size,
                              hipStream_t stream) {
  const float* x         = (const float*)d_in[0];
  const float* patch_w   = (const float*)d_in[1];
  const float* patch_b   = (const float*)d_in[2];
  const float* cls_tok   = (const float*)d_in[3];
  const float* ln1_g     = (const float*)d_in[4];
  const float* ln1_b     = (const float*)d_in[5];
  const float* qkv_w     = (const float*)d_in[6];
  const float* q_bias    = (const float*)d_in[7];
  const float* v_bias    = (const float*)d_in[8];
  const float* rel_table = (const float*)d_in[9];
  const float* proj_w    = (const float*)d_in[10];
  const float* proj_b    = (const float*)d_in[11];
  const float* gamma1    = (const float*)d_in[12];
  const float* ln2_g     = (const float*)d_in[13];
  const float* ln2_b     = (const float*)d_in[14];
  const float* fc1_w     = (const float*)d_in[15];
  const float* fc1_b     = (const float*)d_in[16];
  const float* fc2_w     = (const float*)d_in[17];
  const float* fc2_b     = (const float*)d_in[18];
  const float* gamma2    = (const float*)d_in[19];
  const float* fcn_g     = (const float*)d_in[20];
  const float* fcn_b     = (const float*)d_in[21];
  const int* rel_index   = (const int*)d_in[22];
  float* out = (float*)d_out;

  char* ws = (char*)d_ws;
  size_t off = 0;
  auto take = [&](size_t bytes) {
    char* p = ws + off;
    off += (bytes + 255) & ~(size_t)255;
    return p;
  };
  unsigned short* wl     = (unsigned short*)take((size_t)8257536 * 2);
  unsigned short* pwb    = (unsigned short*)take((size_t)589824 * 2);
  float*          tokf   = (float*)take((size_t)MPAD * 768 * 4);
  unsigned short* hb     = (unsigned short*)take((size_t)MPAD * 768 * 2);
  unsigned short* qkvb   = (unsigned short*)take((size_t)MPAD * 2304 * 2);
  unsigned short* ffb    = (unsigned short*)take((size_t)MPAD * 3072 * 2);
  unsigned short* rpbAll = (unsigned short*)take((size_t)RPB_PER_L * NLAYER * 2);
  unsigned short* xp = ffb;
  unsigned short* ob = hb;
  unsigned short* wl_qkv = wl;
  unsigned short* wl_proj = wl + (size_t)2304 * 768;
  unsigned short* wl_fc1 = wl_proj + (size_t)768 * 768;
  unsigned short* wl_fc2 = wl_fc1 + (size_t)3072 * 768;

  // one-time: rel-pos bias expansion (all layers/heads, fragment order)
  build_rpb<<<(RPB_PER_L * NLAYER + 255) / 256, 256, 0, stream>>>(rel_table, rel_index, rpbAll);

  // patch embed
  cvt4<<<576, 256, 0, stream>>>((const float4*)patch_w, (ushort4*)pwb, 147456);
  build_xp<<<18816, 256, 0, stream>>>(x, xp);
  gemm128<0><<<dim3(6, 50), 256, 0, stream>>>(xp, pwb, tokf, nullptr, patch_b,
                                              nullptr, nullptr, 768, 768);
  fill_cls<<<96, 256, 0, stream>>>(cls_tok, tokf);

  for (int l = 0; l < NLAYER; ++l) {
    cvt_layer<<<6912, 256, 0, stream>>>(
        (const float4*)(qkv_w + (size_t)l * 2304 * 768),
        (const float4*)(proj_w + (size_t)l * 768 * 768),
        (const float4*)(fc1_w + (size_t)l * 3072 * 768),
        (const float4*)(fc2_w + (size_t)l * 768 * 3072), (ushort4*)wl);
    ln_rows<<<MROWS, 256, 0, stream>>>(tokf, hb, ln1_g + l * 768, ln1_b + l * 768);
    gemm128<1><<<dim3(18, 50), 256, 0, stream>>>(hb, wl_qkv, nullptr, qkvb,
                                                 q_bias + l * 768, v_bias + l * 768,
                                                 nullptr, 768, 2304);
    attn_mfma<<<384, 256, 0, stream>>>(qkvb, rpbAll + (size_t)l * RPB_PER_L, ob);
    gemm128<2><<<dim3(6, 50), 256, 0, stream>>>(ob, wl_proj, tokf, nullptr,
                                                proj_b + l * 768, nullptr,
                                                gamma1 + l * 768, 768, 768);
    ln_rows<<<MROWS, 256, 0, stream>>>(tokf, hb, ln2_g + l * 768, ln2_b + l * 768);
    gemm128<3><<<dim3(24, 50), 256, 0, stream>>>(hb, wl_fc1, nullptr, ffb,
                                                 fc1_b + l * 3072, nullptr, nullptr,
                                                 768, 3072);
    gemm128<2><<<dim3(6, 50), 256, 0, stream>>>(ffb, wl_fc2, tokf, nullptr,
                                                fc2_b + l * 768, nullptr,
                                                gamma2 + l * 768, 3072, 768);
  }
  pool_ln<<<32, 256, 0, stream>>>(tokf, fcn_g, fcn_b, out);
}

// Round 4
// 3494.059 us; speedup vs baseline: 3.5908x; 1.0578x over previous
//
#include <hip/hip_runtime.h>

// ---------------------------------------------------------------------------
// USFM ViT (BEiT-style) forward, MI355X gfx950.
// bf16 MFMA GEMMs (swizzled LDS, 128x128 / 64x128 tiles, split-K fc2)
// + MFMA flash-style attention. Round-2 proven skeleton (per-layer cvt).
// ---------------------------------------------------------------------------

#define BATCH 32
#define NTOK 197
#define NLAYER 12
#define NRR 732
#define MROWS (BATCH * NTOK)   // 6304
#define MPAD 6400

#define NKV 224
#define QT_N 13
#define VSTR 232
#define PSTR 232
#define RPB_PER_LH (QT_N * 14 * 4 * 16 * 4)   // 46592
#define RPB_PER_L (RPB_PER_LH * 12)           // 559104
#define WL_ELEMS 8257536                       // qkv+proj+fc1+fc2 per layer

typedef __attribute__((ext_vector_type(8))) short bf16x8_t;
typedef __attribute__((ext_vector_type(4))) float f32x4_t;

__device__ __forceinline__ unsigned short f2bf_rn(float f) {
  unsigned u = __float_as_uint(f);
  unsigned r = (u + 0x7FFFu + ((u >> 16) & 1u)) >> 16;
  return (unsigned short)r;
}
__device__ __forceinline__ float bf2f(unsigned short u) {
  return __uint_as_float(((unsigned)u) << 16);
}

__device__ __forceinline__ void gld16(const unsigned short* g, unsigned short* l) {
  __builtin_amdgcn_global_load_lds(
      (const __attribute__((address_space(1))) unsigned int*)g,
      (__attribute__((address_space(3))) unsigned int*)l, 16, 0, 0);
}

// ---------------------------------------------------------------------------
// fp32 -> bf16 converters
// ---------------------------------------------------------------------------
__global__ void cvt4(const float4* __restrict__ s, ushort4* __restrict__ d, int n4) {
  int i = blockIdx.x * 256 + threadIdx.x;
  if (i >= n4) return;
  float4 v = s[i];
  ushort4 r;
  r.x = f2bf_rn(v.x); r.y = f2bf_rn(v.y); r.z = f2bf_rn(v.z); r.w = f2bf_rn(v.w);
  d[i] = r;
}

__global__ void cvt_layer(const float4* __restrict__ qw, const float4* __restrict__ pw,
                          const float4* __restrict__ f1, const float4* __restrict__ f2,
                          ushort4* __restrict__ dst) {
  const int n_q = 2304 * 768 / 4;
  const int n_p = 768 * 768 / 4;
  const int n_1 = 3072 * 768 / 4;
  int i = blockIdx.x * 256 + threadIdx.x;
  float4 v;
  if (i < n_q) v = qw[i];
  else if (i < n_q + n_p) v = pw[i - n_q];
  else if (i < n_q + n_p + n_1) v = f1[i - n_q - n_p];
  else if (i < n_q + n_p + 2 * n_1) v = f2[i - n_q - n_p - n_1];
  else return;
  ushort4 r;
  r.x = f2bf_rn(v.x); r.y = f2bf_rn(v.y); r.z = f2bf_rn(v.z); r.w = f2bf_rn(v.w);
  dst[i] = r;
}

// ---------------------------------------------------------------------------
// rel-pos bias, fragment order, mask baked in
// ---------------------------------------------------------------------------
__global__ void build_rpb(const float* __restrict__ rt, const int* __restrict__ ridx,
                          unsigned short* __restrict__ dst) {
  int idx = blockIdx.x * 256 + threadIdx.x;
  if (idx >= RPB_PER_L * NLAYER) return;
  int r = idx & 3;
  int fr = (idx >> 2) & 15;
  int fq = (idx >> 6) & 3;
  int t2 = idx >> 8;
  int jt = t2 % 14; t2 /= 14;
  int qt = t2 % QT_N; t2 /= QT_N;
  int h = t2 % 12;
  int l = t2 / 12;
  int row = qt * 16 + fq * 4 + r;
  int col = jt * 16 + fr;
  float v = -30000.f;
  if (row < 197 && col < 197)
    v = rt[((size_t)l * NRR + ridx[row * 197 + col]) * 12 + h];
  dst[idx] = f2bf_rn(v);
}

// ---------------------------------------------------------------------------
// patch unfold
// ---------------------------------------------------------------------------
__global__ void build_xp(const float* __restrict__ x, unsigned short* __restrict__ xp) {
  int idx = blockIdx.x * 256 + threadIdx.x;
  if (idx >= 6272 * 768) return;
  int r = idx / 768, c = idx - r * 768;
  int b = r / 196, p = r - b * 196;
  int gy = p / 14, gx = p - gy * 14;
  int ch = c >> 8, rem = c & 255, py = rem >> 4, px = rem & 15;
  float v = x[(((size_t)b * 3 + ch) * 224 + gy * 16 + py) * 224 + gx * 16 + px];
  xp[(size_t)(b * 197 + 1 + p) * 768 + c] = f2bf_rn(v);
}

__global__ void fill_cls(const float* __restrict__ cls, float* __restrict__ tok) {
  int idx = blockIdx.x * 256 + threadIdx.x;
  int b = idx / 768, d = idx - b * 768;
  tok[(size_t)(b * 197) * 768 + d] = cls[d];
}

// ---------------------------------------------------------------------------
// LayerNorm rows: fp32 in -> bf16 out
// ---------------------------------------------------------------------------
__global__ __launch_bounds__(256) void ln_rows(const float* __restrict__ x,
                                               unsigned short* __restrict__ y,
                                               const float* __restrict__ g,
                                               const float* __restrict__ b) {
  int row = blockIdx.x;
  const float* xr = x + (size_t)row * 768;
  int t = threadIdx.x;
  float v0 = xr[t], v1 = xr[t + 256], v2 = xr[t + 512];
  float s = v0 + v1 + v2;
  float q = v0 * v0 + v1 * v1 + v2 * v2;
  for (int off = 32; off; off >>= 1) { s += __shfl_xor(s, off); q += __shfl_xor(q, off); }
  __shared__ float rs[4], rq[4];
  int wave = t >> 6;
  if ((t & 63) == 0) { rs[wave] = s; rq[wave] = q; }
  __syncthreads();
  s = rs[0] + rs[1] + rs[2] + rs[3];
  q = rq[0] + rq[1] + rq[2] + rq[3];
  float mean = s * (1.f / 768.f);
  float var = q * (1.f / 768.f) - mean * mean;
  float rstd = rsqrtf(var + 1e-5f);
  unsigned short* yr = y + (size_t)row * 768;
  yr[t]       = f2bf_rn((v0 - mean) * rstd * g[t]       + b[t]);
  yr[t + 256] = f2bf_rn((v1 - mean) * rstd * g[t + 256] + b[t + 256]);
  yr[t + 512] = f2bf_rn((v2 - mean) * rstd * g[t + 512] + b[t + 512]);
}

// ---------------------------------------------------------------------------
// MFMA GEMM: out = A[M,K] @ Bw[N,K]^T, bf16 in, fp32 accum.
// BM x 128 tile (BM=128: 4 waves of 64x64; BM=64: 4 waves of 32x64).
// LDS chunk-swizzle: store-side lane reads global chunk (lane&3)^((lane>>3)&3)
// so LDS slot j of row r holds chunk j^((r>>1)&3); fragment read uses slot
// fq^((fr>>1)&3) -> same data, conflict-free octets.
// SPLIT>1: K split over blockIdx.z, fp32 atomicAdd epilogue (MODE 2 only).
// MODE 0: Cf = acc + bias; 1: qkv epilogue; 2: residual; 3: gelu
// ---------------------------------------------------------------------------
template <int MODE, int BM, int SPLIT>
__global__ __launch_bounds__(256, 2) void gemm_t(
    const unsigned short* __restrict__ A, const unsigned short* __restrict__ Bw,
    float* __restrict__ Cf, unsigned short* __restrict__ Cb,
    const float* __restrict__ bias, const float* __restrict__ bias2,
    const float* __restrict__ gamma, int K, int N) {
  constexpr int MI = BM / 32;  // acc tiles in M per wave
  __shared__ __align__(16) unsigned short As[BM * 32];
  __shared__ __align__(16) unsigned short Bs[128 * 32];
  const int tid = threadIdx.x;
  const int wave = tid >> 6, lane = tid & 63;
  const int m0 = blockIdx.y * BM, n0 = blockIdx.x * 128;
  const int wm = (wave & 1) * (MI * 16), wn = (wave >> 1) * 64;
  const int KS = K / SPLIT;
  const int kbase = blockIdx.z * KS;
  f32x4_t acc[MI][4] = {};
  const int srow = lane >> 2;
  const int scol = ((lane & 3) ^ ((lane >> 3) & 3)) * 8;   // swizzled source chunk
  const unsigned short* Abase = A + (size_t)(m0 + srow) * K + kbase + scol;
  const unsigned short* Bbase = Bw + (size_t)(n0 + srow) * K + kbase + scol;
  const int fr = lane & 15, fq = lane >> 4;
  const int rchunk = (fq ^ ((fr >> 1) & 3)) * 8;           // swizzled read chunk
  for (int k0 = 0; k0 < KS; k0 += 32) {
    __syncthreads();
#pragma unroll
    for (int u0 = 0; u0 < BM / 64; ++u0) {
      int u = wave + u0 * 4;
      gld16(Abase + (size_t)(u * 16) * K + k0, As + u * 512);
    }
#pragma unroll
    for (int u0 = 0; u0 < 2; ++u0) {
      int u = wave + u0 * 4;
      gld16(Bbase + (size_t)(u * 16) * K + k0, Bs + u * 512);
    }
    __syncthreads();
    bf16x8_t af[MI], bfr[4];
#pragma unroll
    for (int i = 0; i < MI; ++i)
      af[i] = *(const bf16x8_t*)(As + (wm + i * 16 + fr) * 32 + rchunk);
#pragma unroll
    for (int j = 0; j < 4; ++j)
      bfr[j] = *(const bf16x8_t*)(Bs + (wn + j * 16 + fr) * 32 + rchunk);
#pragma unroll
    for (int i = 0; i < MI; ++i)
#pragma unroll
      for (int j = 0; j < 4; ++j)
        acc[i][j] = __builtin_amdgcn_mfma_f32_16x16x32_bf16(af[i], bfr[j], acc[i][j], 0, 0, 0);
  }
  const int er = (lane >> 4) * 4;
  const int ec = lane & 15;
#pragma unroll
  for (int i = 0; i < MI; ++i) {
#pragma unroll
    for (int j = 0; j < 4; ++j) {
#pragma unroll
      for (int r = 0; r < 4; ++r) {
        int row = m0 + wm + i * 16 + er + r;
        int col = n0 + wn + j * 16 + ec;
        float v = acc[i][j][r];
        size_t idx = (size_t)row * N + col;
        if constexpr (MODE == 0) {
          Cf[idx] = v + bias[col];
        } else if constexpr (MODE == 1) {
          float bv = (col < 768) ? bias[col] : (col >= 1536 ? bias2[col - 1536] : 0.f);
          v += bv;
          if (col < 768) v *= 0.125f;  // SCALE = 64^-0.5
          Cb[idx] = f2bf_rn(v);
        } else if constexpr (MODE == 2) {
          if constexpr (SPLIT == 1) {
            Cf[idx] = Cf[idx] + gamma[col] * (v + bias[col]);
          } else {
            float add = gamma[col] * (v + (blockIdx.z == 0 ? bias[col] : 0.f));
            atomicAdd(&Cf[idx], add);
          }
        } else {
          float tt = v + bias[col];
          float gv = 0.5f * tt * (1.f + erff(tt * 0.70710678118654752f));
          Cb[idx] = f2bf_rn(gv);
        }
      }
    }
  }
}

// ---------------------------------------------------------------------------
// MFMA attention: one block per (b,h), 4 waves, q-tiles striped over waves.
// ---------------------------------------------------------------------------
__global__ __launch_bounds__(256) void attn_mfma(
    const unsigned short* __restrict__ qkv,
    const unsigned short* __restrict__ rpb,
    unsigned short* __restrict__ o) {
  const int bh = blockIdx.x;
  const int b = bh / 12, h = bh - b * 12;
  __shared__ __align__(16) unsigned short Vt[64 * VSTR];
  __shared__ __align__(16) unsigned short Pls[4][16 * PSTR];
  const int t = threadIdx.x;
  const int wave = t >> 6, lane = t & 63;
  const int fr = lane & 15, fq = lane >> 4;
  const size_t qbase = (size_t)(b * 197) * 2304 + h * 64;
  const unsigned short* rph = rpb + (size_t)h * RPB_PER_LH;

  for (int idx = t; idx < NKV * 16; idx += 256) {
    int j = idx >> 4, d0 = (idx & 15) * 4;
    ushort4 v = *(const ushort4*)(qkv + qbase + 1536 + (size_t)j * 2304 + d0);
    Vt[(d0 + 0) * VSTR + j] = v.x;
    Vt[(d0 + 1) * VSTR + j] = v.y;
    Vt[(d0 + 2) * VSTR + j] = v.z;
    Vt[(d0 + 3) * VSTR + j] = v.w;
  }
  __syncthreads();

  unsigned short* P = &Pls[wave][0];
  for (int qt = wave; qt < QT_N; qt += 4) {
    const unsigned short* qrow = qkv + qbase + (size_t)(qt * 16 + fr) * 2304 + fq * 8;
    bf16x8_t qa0 = *(const bf16x8_t*)(qrow);
    bf16x8_t qa1 = *(const bf16x8_t*)(qrow + 32);
    f32x4_t S[14];
#pragma unroll
    for (int jt = 0; jt < 14; ++jt) {
      const unsigned short* krow = qkv + qbase + 768 + (size_t)(jt * 16 + fr) * 2304 + fq * 8;
      bf16x8_t kb0 = *(const bf16x8_t*)(krow);
      bf16x8_t kb1 = *(const bf16x8_t*)(krow + 32);
      f32x4_t s = {};
      s = __builtin_amdgcn_mfma_f32_16x16x32_bf16(qa0, kb0, s, 0, 0, 0);
      s = __builtin_amdgcn_mfma_f32_16x16x32_bf16(qa1, kb1, s, 0, 0, 0);
      ushort4 rb = *(const ushort4*)(rph + ((size_t)(qt * 14 + jt) * 4 + fq) * 64 + fr * 4);
      s[0] += bf2f(rb.x); s[1] += bf2f(rb.y); s[2] += bf2f(rb.z); s[3] += bf2f(rb.w);
      S[jt] = s;
    }
    float mx[4], sum[4];
#pragma unroll
    for (int r = 0; r < 4; ++r) mx[r] = S[0][r];
#pragma unroll
    for (int jt = 1; jt < 14; ++jt)
#pragma unroll
      for (int r = 0; r < 4; ++r) mx[r] = fmaxf(mx[r], S[jt][r]);
#pragma unroll
    for (int r = 0; r < 4; ++r) {
      for (int off = 1; off < 16; off <<= 1) mx[r] = fmaxf(mx[r], __shfl_xor(mx[r], off));
      sum[r] = 0.f;
    }
#pragma unroll
    for (int jt = 0; jt < 14; ++jt) {
#pragma unroll
      for (int r = 0; r < 4; ++r) {
        float p = __expf(S[jt][r] - mx[r]);
        sum[r] += p;
        P[(fq * 4 + r) * PSTR + jt * 16 + fr] = f2bf_rn(p);
      }
    }
    float rinv[4];
#pragma unroll
    for (int r = 0; r < 4; ++r) {
      for (int off = 1; off < 16; off <<= 1) sum[r] += __shfl_xor(sum[r], off);
      rinv[r] = 1.f / sum[r];
    }
    bf16x8_t pa[7];
#pragma unroll
    for (int ks = 0; ks < 7; ++ks)
      pa[ks] = *(const bf16x8_t*)(P + fr * PSTR + ks * 32 + fq * 8);
#pragma unroll
    for (int nt = 0; nt < 4; ++nt) {
      f32x4_t O = {};
#pragma unroll
      for (int ks = 0; ks < 7; ++ks) {
        bf16x8_t vb = *(const bf16x8_t*)(Vt + (nt * 16 + fr) * VSTR + ks * 32 + fq * 8);
        O = __builtin_amdgcn_mfma_f32_16x16x32_bf16(pa[ks], vb, O, 0, 0, 0);
      }
#pragma unroll
      for (int r = 0; r < 4; ++r) {
        int row = qt * 16 + fq * 4 + r;
        if (row < 197)
          o[(size_t)(b * 197 + row) * 768 + h * 64 + nt * 16 + fr] = f2bf_rn(O[r] * rinv[r]);
      }
    }
  }
}

// ---------------------------------------------------------------------------
// final: mean over patch tokens + fc_norm
// ---------------------------------------------------------------------------
__global__ __launch_bounds__(256) void pool_ln(const float* __restrict__ tok,
                                               const float* __restrict__ g,
                                               const float* __restrict__ bb,
                                               float* __restrict__ out) {
  int b = blockIdx.x;
  __shared__ float pool[768];
  int t = threadIdx.x;
  for (int c = t; c < 768; c += 256) {
    float s = 0.f;
    const float* p = tok + (size_t)(b * 197 + 1) * 768 + c;
    for (int i = 0; i < 196; ++i) s += p[(size_t)i * 768];
    pool[c] = s * (1.f / 196.f);
  }
  __syncthreads();
  float s = 0.f, q = 0.f;
  for (int c = t; c < 768; c += 256) { float v = pool[c]; s += v; q += v * v; }
  for (int off = 32; off; off >>= 1) { s += __shfl_xor(s, off); q += __shfl_xor(q, off); }
  __shared__ float rs[4], rq[4];
  if ((t & 63) == 0) { rs[t >> 6] = s; rq[t >> 6] = q; }
  __syncthreads();
  s = rs[0] + rs[1] + rs[2] + rs[3];
  q = rq[0] + rq[1] + rq[2] + rq[3];
  float mean = s * (1.f / 768.f);
  float var = q * (1.f / 768.f) - mean * mean;
  float rstd = rsqrtf(var + 1e-5f);
  for (int c = t; c < 768; c += 256)
    out[(size_t)b * 768 + c] = (pool[c] - mean) * rstd * g[c] + bb[c];
}

// ---------------------------------------------------------------------------
extern "C" void kernel_launch(void* const* d_in, const int* in_sizes, int n_in,
                              void* d_out, int out_size, void* d_ws, size_t ws_size,
                              hipStream_t stream) {
  const float* x         = (const float*)d_in[0];
  const float* patch_w   = (const float*)d_in[1];
  const float* patch_b   = (const float*)d_in[2];
  const float* cls_tok   = (const float*)d_in[3];
  const float* ln1_g     = (const float*)d_in[4];
  const float* ln1_b     = (const float*)d_in[5];
  const float* qkv_w     = (const float*)d_in[6];
  const float* q_bias    = (const float*)d_in[7];
  const float* v_bias    = (const float*)d_in[8];
  const float* rel_table = (const float*)d_in[9];
  const float* proj_w    = (const float*)d_in[10];
  const float* proj_b    = (const float*)d_in[11];
  const float* gamma1    = (const float*)d_in[12];
  const float* ln2_g     = (const float*)d_in[13];
  const float* ln2_b     = (const float*)d_in[14];
  const float* fc1_w     = (const float*)d_in[15];
  const float* fc1_b     = (const float*)d_in[16];
  const float* fc2_w     = (const float*)d_in[17];
  const float* fc2_b     = (const float*)d_in[18];
  const float* gamma2    = (const float*)d_in[19];
  const float* fcn_g     = (const float*)d_in[20];
  const float* fcn_b     = (const float*)d_in[21];
  const int* rel_index   = (const int*)d_in[22];
  float* out = (float*)d_out;

  char* ws = (char*)d_ws;
  size_t off = 0;
  auto take = [&](size_t bytes) {
    char* p = ws + off;
    off += (bytes + 255) & ~(size_t)255;
    return p;
  };
  unsigned short* wl     = (unsigned short*)take((size_t)WL_ELEMS * 2);
  unsigned short* pwb    = (unsigned short*)take((size_t)589824 * 2);
  float*          tokf   = (float*)take((size_t)MPAD * 768 * 4);
  unsigned short* hb     = (unsigned short*)take((size_t)MPAD * 768 * 2);
  unsigned short* qkvb   = (unsigned short*)take((size_t)MPAD * 2304 * 2);
  unsigned short* ffb    = (unsigned short*)take((size_t)MPAD * 3072 * 2);
  unsigned short* rpbAll = (unsigned short*)take((size_t)RPB_PER_L * NLAYER * 2);
  unsigned short* xp = ffb;
  unsigned short* ob = hb;
  unsigned short* wl_qkv = wl;
  unsigned short* wl_proj = wl + (size_t)2304 * 768;
  unsigned short* wl_fc1 = wl_proj + (size_t)768 * 768;
  unsigned short* wl_fc2 = wl_fc1 + (size_t)3072 * 768;

  // one-time: rel-pos bias expansion
  build_rpb<<<(RPB_PER_L * NLAYER + 255) / 256, 256, 0, stream>>>(rel_table, rel_index, rpbAll);

  // patch embed
  cvt4<<<576, 256, 0, stream>>>((const float4*)patch_w, (ushort4*)pwb, 147456);
  build_xp<<<18816, 256, 0, stream>>>(x, xp);
  gemm_t<0, 64, 1><<<dim3(6, 100), 256, 0, stream>>>(xp, pwb, tokf, nullptr, patch_b,
                                                     nullptr, nullptr, 768, 768);
  fill_cls<<<96, 256, 0, stream>>>(cls_tok, tokf);

  for (int l = 0; l < NLAYER; ++l) {
    cvt_layer<<<(WL_ELEMS / 4 + 255) / 256, 256, 0, stream>>>(
        (const float4*)(qkv_w + (size_t)l * 2304 * 768),
        (const float4*)(proj_w + (size_t)l * 768 * 768),
        (const float4*)(fc1_w + (size_t)l * 3072 * 768),
        (const float4*)(fc2_w + (size_t)l * 768 * 3072), (ushort4*)wl);
    ln_rows<<<MROWS, 256, 0, stream>>>(tokf, hb, ln1_g + l * 768, ln1_b + l * 768);
    gemm_t<1, 128, 1><<<dim3(18, 50), 256, 0, stream>>>(hb, wl_qkv, nullptr, qkvb,
                                                        q_bias + l * 768, v_bias + l * 768,
                                                        nullptr, 768, 2304);
    attn_mfma<<<384, 256, 0, stream>>>(qkvb, rpbAll + (size_t)l * RPB_PER_L, ob);
    gemm_t<2, 64, 1><<<dim3(6, 100), 256, 0, stream>>>(ob, wl_proj, tokf, nullptr,
                                                       proj_b + l * 768, nullptr,
                                                       gamma1 + l * 768, 768, 768);
    ln_rows<<<MROWS, 256, 0, stream>>>(tokf, hb, ln2_g + l * 768, ln2_b + l * 768);
    gemm_t<3, 128, 1><<<dim3(24, 50), 256, 0, stream>>>(hb, wl_fc1, nullptr, ffb,
                                                        fc1_b + l * 3072, nullptr, nullptr,
                                                        768, 3072);
    gemm_t<2, 64, 2><<<dim3(6, 100, 2), 256, 0, stream>>>(ffb, wl_fc2, tokf, nullptr,
                                                          fc2_b + l * 768, nullptr,
                                                          gamma2 + l * 768, 3072, 768);
  }
  pool_ln<<<32, 256, 0, stream>>>(tokf, fcn_g, fcn_b, out);
}

// Round 5
// 3361.616 us; speedup vs baseline: 3.7322x; 1.0394x over previous
//
#include <hip/hip_runtime.h>

// ---------------------------------------------------------------------------
// USFM ViT (BEiT-style) forward, MI355X gfx950.
// bf16 MFMA GEMMs (swizzled LDS, BK=64 twin-buffer staging, 128/64-row tiles)
// + MFMA flash-style attention.
// ---------------------------------------------------------------------------

#define BATCH 32
#define NTOK 197
#define NLAYER 12
#define NRR 732
#define MROWS (BATCH * NTOK)   // 6304
#define MPAD 6400

#define NKV 224
#define QT_N 13
#define VSTR 232
#define PSTR 232
#define RPB_PER_LH (QT_N * 14 * 4 * 16 * 4)   // 46592
#define RPB_PER_L (RPB_PER_LH * 12)           // 559104
#define WL_ELEMS 8257536                       // qkv+proj+fc1+fc2 per layer

typedef __attribute__((ext_vector_type(8))) short bf16x8_t;
typedef __attribute__((ext_vector_type(4))) float f32x4_t;

__device__ __forceinline__ unsigned short f2bf_rn(float f) {
  unsigned u = __float_as_uint(f);
  unsigned r = (u + 0x7FFFu + ((u >> 16) & 1u)) >> 16;
  return (unsigned short)r;
}
__device__ __forceinline__ float bf2f(unsigned short u) {
  return __uint_as_float(((unsigned)u) << 16);
}

__device__ __forceinline__ void gld16(const unsigned short* g, unsigned short* l) {
  __builtin_amdgcn_global_load_lds(
      (const __attribute__((address_space(1))) unsigned int*)g,
      (__attribute__((address_space(3))) unsigned int*)l, 16, 0, 0);
}

// ---------------------------------------------------------------------------
// fp32 -> bf16 converters
// ---------------------------------------------------------------------------
__global__ void cvt4(const float4* __restrict__ s, ushort4* __restrict__ d, int n4) {
  int i = blockIdx.x * 256 + threadIdx.x;
  if (i >= n4) return;
  float4 v = s[i];
  ushort4 r;
  r.x = f2bf_rn(v.x); r.y = f2bf_rn(v.y); r.z = f2bf_rn(v.z); r.w = f2bf_rn(v.w);
  d[i] = r;
}

__global__ void cvt_layer(const float4* __restrict__ qw, const float4* __restrict__ pw,
                          const float4* __restrict__ f1, const float4* __restrict__ f2,
                          ushort4* __restrict__ dst) {
  const int n_q = 2304 * 768 / 4;
  const int n_p = 768 * 768 / 4;
  const int n_1 = 3072 * 768 / 4;
  int i = blockIdx.x * 256 + threadIdx.x;
  float4 v;
  if (i < n_q) v = qw[i];
  else if (i < n_q + n_p) v = pw[i - n_q];
  else if (i < n_q + n_p + n_1) v = f1[i - n_q - n_p];
  else if (i < n_q + n_p + 2 * n_1) v = f2[i - n_q - n_p - n_1];
  else return;
  ushort4 r;
  r.x = f2bf_rn(v.x); r.y = f2bf_rn(v.y); r.z = f2bf_rn(v.z); r.w = f2bf_rn(v.w);
  dst[i] = r;
}

// ---------------------------------------------------------------------------
// rel-pos bias, fragment order, mask baked in
// ---------------------------------------------------------------------------
__global__ void build_rpb(const float* __restrict__ rt, const int* __restrict__ ridx,
                          unsigned short* __restrict__ dst) {
  int idx = blockIdx.x * 256 + threadIdx.x;
  if (idx >= RPB_PER_L * NLAYER) return;
  int r = idx & 3;
  int fr = (idx >> 2) & 15;
  int fq = (idx >> 6) & 3;
  int t2 = idx >> 8;
  int jt = t2 % 14; t2 /= 14;
  int qt = t2 % QT_N; t2 /= QT_N;
  int h = t2 % 12;
  int l = t2 / 12;
  int row = qt * 16 + fq * 4 + r;
  int col = jt * 16 + fr;
  float v = -30000.f;
  if (row < 197 && col < 197)
    v = rt[((size_t)l * NRR + ridx[row * 197 + col]) * 12 + h];
  dst[idx] = f2bf_rn(v);
}

// ---------------------------------------------------------------------------
// patch unfold
// ---------------------------------------------------------------------------
__global__ void build_xp(const float* __restrict__ x, unsigned short* __restrict__ xp) {
  int idx = blockIdx.x * 256 + threadIdx.x;
  if (idx >= 6272 * 768) return;
  int r = idx / 768, c = idx - r * 768;
  int b = r / 196, p = r - b * 196;
  int gy = p / 14, gx = p - gy * 14;
  int ch = c >> 8, rem = c & 255, py = rem >> 4, px = rem & 15;
  float v = x[(((size_t)b * 3 + ch) * 224 + gy * 16 + py) * 224 + gx * 16 + px];
  xp[(size_t)(b * 197 + 1 + p) * 768 + c] = f2bf_rn(v);
}

__global__ void fill_cls(const float* __restrict__ cls, float* __restrict__ tok) {
  int idx = blockIdx.x * 256 + threadIdx.x;
  int b = idx / 768, d = idx - b * 768;
  tok[(size_t)(b * 197) * 768 + d] = cls[d];
}

// ---------------------------------------------------------------------------
// LayerNorm rows: fp32 in -> bf16 out
// ---------------------------------------------------------------------------
__global__ __launch_bounds__(256) void ln_rows(const float* __restrict__ x,
                                               unsigned short* __restrict__ y,
                                               const float* __restrict__ g,
                                               const float* __restrict__ b) {
  int row = blockIdx.x;
  const float* xr = x + (size_t)row * 768;
  int t = threadIdx.x;
  float v0 = xr[t], v1 = xr[t + 256], v2 = xr[t + 512];
  float s = v0 + v1 + v2;
  float q = v0 * v0 + v1 * v1 + v2 * v2;
  for (int off = 32; off; off >>= 1) { s += __shfl_xor(s, off); q += __shfl_xor(q, off); }
  __shared__ float rs[4], rq[4];
  int wave = t >> 6;
  if ((t & 63) == 0) { rs[wave] = s; rq[wave] = q; }
  __syncthreads();
  s = rs[0] + rs[1] + rs[2] + rs[3];
  q = rq[0] + rq[1] + rq[2] + rq[3];
  float mean = s * (1.f / 768.f);
  float var = q * (1.f / 768.f) - mean * mean;
  float rstd = rsqrtf(var + 1e-5f);
  unsigned short* yr = y + (size_t)row * 768;
  yr[t]       = f2bf_rn((v0 - mean) * rstd * g[t]       + b[t]);
  yr[t + 256] = f2bf_rn((v1 - mean) * rstd * g[t + 256] + b[t + 256]);
  yr[t + 512] = f2bf_rn((v2 - mean) * rstd * g[t + 512] + b[t + 512]);
}

// ---------------------------------------------------------------------------
// MFMA GEMM: out = A[M,K] @ Bw[N,K]^T, bf16 in, fp32 accum.
// BM x 128 tile; BK=64 staged as two 32-k LDS buffers, ONE barrier pair per
// 64-K (halves barrier/drain count vs BK=32).
// LDS chunk-swizzle per buffer: store chunk (lane&3)^((lane>>3)&3); read
// chunk fq^((fr>>1)&3) -> conflict-free octets (verified r4: conflicts=0).
// MODE 0: Cf = acc + bias; 1: qkv epilogue; 2: residual; 3: gelu
// ---------------------------------------------------------------------------
template <int MODE, int BM>
__global__ __launch_bounds__(256, 2) void gemm_t(
    const unsigned short* __restrict__ A, const unsigned short* __restrict__ Bw,
    float* __restrict__ Cf, unsigned short* __restrict__ Cb,
    const float* __restrict__ bias, const float* __restrict__ bias2,
    const float* __restrict__ gamma, int K, int N) {
  constexpr int MI = BM / 32;  // acc tiles in M per wave
  __shared__ __align__(16) unsigned short As[2][BM * 32];
  __shared__ __align__(16) unsigned short Bs[2][128 * 32];
  const int tid = threadIdx.x;
  const int wave = tid >> 6, lane = tid & 63;
  const int m0 = blockIdx.y * BM, n0 = blockIdx.x * 128;
  const int wm = (wave & 1) * (MI * 16), wn = (wave >> 1) * 64;
  f32x4_t acc[MI][4] = {};
  const int srow = lane >> 2;
  const int scol = ((lane & 3) ^ ((lane >> 3) & 3)) * 8;   // swizzled source chunk
  const unsigned short* Abase = A + (size_t)(m0 + srow) * K + scol;
  const unsigned short* Bbase = Bw + (size_t)(n0 + srow) * K + scol;
  const int fr = lane & 15, fq = lane >> 4;
  const int rchunk = (fq ^ ((fr >> 1) & 3)) * 8;           // swizzled read chunk
  for (int k0 = 0; k0 < K; k0 += 64) {
    __syncthreads();
#pragma unroll
    for (int s = 0; s < 2; ++s) {
#pragma unroll
      for (int u0 = 0; u0 < BM / 64; ++u0) {
        int u = wave + u0 * 4;
        gld16(Abase + (size_t)(u * 16) * K + k0 + s * 32, &As[s][u * 512]);
      }
#pragma unroll
      for (int u0 = 0; u0 < 2; ++u0) {
        int u = wave + u0 * 4;
        gld16(Bbase + (size_t)(u * 16) * K + k0 + s * 32, &Bs[s][u * 512]);
      }
    }
    __syncthreads();
#pragma unroll
    for (int s = 0; s < 2; ++s) {
      bf16x8_t af[MI], bfr[4];
#pragma unroll
      for (int i = 0; i < MI; ++i)
        af[i] = *(const bf16x8_t*)(&As[s][(wm + i * 16 + fr) * 32 + rchunk]);
#pragma unroll
      for (int j = 0; j < 4; ++j)
        bfr[j] = *(const bf16x8_t*)(&Bs[s][(wn + j * 16 + fr) * 32 + rchunk]);
#pragma unroll
      for (int i = 0; i < MI; ++i)
#pragma unroll
        for (int j = 0; j < 4; ++j)
          acc[i][j] = __builtin_amdgcn_mfma_f32_16x16x32_bf16(af[i], bfr[j], acc[i][j], 0, 0, 0);
    }
  }
  const int er = (lane >> 4) * 4;
  const int ec = lane & 15;
#pragma unroll
  for (int i = 0; i < MI; ++i) {
#pragma unroll
    for (int j = 0; j < 4; ++j) {
#pragma unroll
      for (int r = 0; r < 4; ++r) {
        int row = m0 + wm + i * 16 + er + r;
        int col = n0 + wn + j * 16 + ec;
        float v = acc[i][j][r];
        size_t idx = (size_t)row * N + col;
        if constexpr (MODE == 0) {
          Cf[idx] = v + bias[col];
        } else if constexpr (MODE == 1) {
          float bv = (col < 768) ? bias[col] : (col >= 1536 ? bias2[col - 1536] : 0.f);
          v += bv;
          if (col < 768) v *= 0.125f;  // SCALE = 64^-0.5
          Cb[idx] = f2bf_rn(v);
        } else if constexpr (MODE == 2) {
          Cf[idx] = Cf[idx] + gamma[col] * (v + bias[col]);
        } else {
          float tt = v + bias[col];
          float gv = 0.5f * tt * (1.f + erff(tt * 0.70710678118654752f));
          Cb[idx] = f2bf_rn(gv);
        }
      }
    }
  }
}

// ---------------------------------------------------------------------------
// MFMA attention: one block per (b,h), 4 waves, q-tiles striped over waves.
// ---------------------------------------------------------------------------
__global__ __launch_bounds__(256) void attn_mfma(
    const unsigned short* __restrict__ qkv,
    const unsigned short* __restrict__ rpb,
    unsigned short* __restrict__ o) {
  const int bh = blockIdx.x;
  const int b = bh / 12, h = bh - b * 12;
  __shared__ __align__(16) unsigned short Vt[64 * VSTR];
  __shared__ __align__(16) unsigned short Pls[4][16 * PSTR];
  const int t = threadIdx.x;
  const int wave = t >> 6, lane = t & 63;
  const int fr = lane & 15, fq = lane >> 4;
  const size_t qbase = (size_t)(b * 197) * 2304 + h * 64;
  const unsigned short* rph = rpb + (size_t)h * RPB_PER_LH;

  for (int idx = t; idx < NKV * 16; idx += 256) {
    int j = idx >> 4, d0 = (idx & 15) * 4;
    ushort4 v = *(const ushort4*)(qkv + qbase + 1536 + (size_t)j * 2304 + d0);
    Vt[(d0 + 0) * VSTR + j] = v.x;
    Vt[(d0 + 1) * VSTR + j] = v.y;
    Vt[(d0 + 2) * VSTR + j] = v.z;
    Vt[(d0 + 3) * VSTR + j] = v.w;
  }
  __syncthreads();

  unsigned short* P = &Pls[wave][0];
  for (int qt = wave; qt < QT_N; qt += 4) {
    const unsigned short* qrow = qkv + qbase + (size_t)(qt * 16 + fr) * 2304 + fq * 8;
    bf16x8_t qa0 = *(const bf16x8_t*)(qrow);
    bf16x8_t qa1 = *(const bf16x8_t*)(qrow + 32);
    f32x4_t S[14];
#pragma unroll
    for (int jt = 0; jt < 14; ++jt) {
      const unsigned short* krow = qkv + qbase + 768 + (size_t)(jt * 16 + fr) * 2304 + fq * 8;
      bf16x8_t kb0 = *(const bf16x8_t*)(krow);
      bf16x8_t kb1 = *(const bf16x8_t*)(krow + 32);
      f32x4_t s = {};
      s = __builtin_amdgcn_mfma_f32_16x16x32_bf16(qa0, kb0, s, 0, 0, 0);
      s = __builtin_amdgcn_mfma_f32_16x16x32_bf16(qa1, kb1, s, 0, 0, 0);
      ushort4 rb = *(const ushort4*)(rph + ((size_t)(qt * 14 + jt) * 4 + fq) * 64 + fr * 4);
      s[0] += bf2f(rb.x); s[1] += bf2f(rb.y); s[2] += bf2f(rb.z); s[3] += bf2f(rb.w);
      S[jt] = s;
    }
    float mx[4], sum[4];
#pragma unroll
    for (int r = 0; r < 4; ++r) mx[r] = S[0][r];
#pragma unroll
    for (int jt = 1; jt < 14; ++jt)
#pragma unroll
      for (int r = 0; r < 4; ++r) mx[r] = fmaxf(mx[r], S[jt][r]);
#pragma unroll
    for (int r = 0; r < 4; ++r) {
      for (int off = 1; off < 16; off <<= 1) mx[r] = fmaxf(mx[r], __shfl_xor(mx[r], off));
      sum[r] = 0.f;
    }
#pragma unroll
    for (int jt = 0; jt < 14; ++jt) {
#pragma unroll
      for (int r = 0; r < 4; ++r) {
        float p = __expf(S[jt][r] - mx[r]);
        sum[r] += p;
        P[(fq * 4 + r) * PSTR + jt * 16 + fr] = f2bf_rn(p);
      }
    }
    float rinv[4];
#pragma unroll
    for (int r = 0; r < 4; ++r) {
      for (int off = 1; off < 16; off <<= 1) sum[r] += __shfl_xor(sum[r], off);
      rinv[r] = 1.f / sum[r];
    }
    bf16x8_t pa[7];
#pragma unroll
    for (int ks = 0; ks < 7; ++ks)
      pa[ks] = *(const bf16x8_t*)(P + fr * PSTR + ks * 32 + fq * 8);
#pragma unroll
    for (int nt = 0; nt < 4; ++nt) {
      f32x4_t O = {};
#pragma unroll
      for (int ks = 0; ks < 7; ++ks) {
        bf16x8_t vb = *(const bf16x8_t*)(Vt + (nt * 16 + fr) * VSTR + ks * 32 + fq * 8);
        O = __builtin_amdgcn_mfma_f32_16x16x32_bf16(pa[ks], vb, O, 0, 0, 0);
      }
#pragma unroll
      for (int r = 0; r < 4; ++r) {
        int row = qt * 16 + fq * 4 + r;
        if (row < 197)
          o[(size_t)(b * 197 + row) * 768 + h * 64 + nt * 16 + fr] = f2bf_rn(O[r] * rinv[r]);
      }
    }
  }
}

// ---------------------------------------------------------------------------
// final: mean over patch tokens + fc_norm
// ---------------------------------------------------------------------------
__global__ __launch_bounds__(256) void pool_ln(const float* __restrict__ tok,
                                               const float* __restrict__ g,
                                               const float* __restrict__ bb,
                                               float* __restrict__ out) {
  int b = blockIdx.x;
  __shared__ float pool[768];
  int t = threadIdx.x;
  for (int c = t; c < 768; c += 256) {
    float s = 0.f;
    const float* p = tok + (size_t)(b * 197 + 1) * 768 + c;
    for (int i = 0; i < 196; ++i) s += p[(size_t)i * 768];
    pool[c] = s * (1.f / 196.f);
  }
  __syncthreads();
  float s = 0.f, q = 0.f;
  for (int c = t; c < 768; c += 256) { float v = pool[c]; s += v; q += v * v; }
  for (int off = 32; off; off >>= 1) { s += __shfl_xor(s, off); q += __shfl_xor(q, off); }
  __shared__ float rs[4], rq[4];
  if ((t & 63) == 0) { rs[t >> 6] = s; rq[t >> 6] = q; }
  __syncthreads();
  s = rs[0] + rs[1] + rs[2] + rs[3];
  q = rq[0] + rq[1] + rq[2] + rq[3];
  float mean = s * (1.f / 768.f);
  float var = q * (1.f / 768.f) - mean * mean;
  float rstd = rsqrtf(var + 1e-5f);
  for (int c = t; c < 768; c += 256)
    out[(size_t)b * 768 + c] = (pool[c] - mean) * rstd * g[c] + bb[c];
}

// ---------------------------------------------------------------------------
extern "C" void kernel_launch(void* const* d_in, const int* in_sizes, int n_in,
                              void* d_out, int out_size, void* d_ws, size_t ws_size,
                              hipStream_t stream) {
  const float* x         = (const float*)d_in[0];
  const float* patch_w   = (const float*)d_in[1];
  const float* patch_b   = (const float*)d_in[2];
  const float* cls_tok   = (const float*)d_in[3];
  const float* ln1_g     = (const float*)d_in[4];
  const float* ln1_b     = (const float*)d_in[5];
  const float* qkv_w     = (const float*)d_in[6];
  const float* q_bias    = (const float*)d_in[7];
  const float* v_bias    = (const float*)d_in[8];
  const float* rel_table = (const float*)d_in[9];
  const float* proj_w    = (const float*)d_in[10];
  const float* proj_b    = (const float*)d_in[11];
  const float* gamma1    = (const float*)d_in[12];
  const float* ln2_g     = (const float*)d_in[13];
  const float* ln2_b     = (const float*)d_in[14];
  const float* fc1_w     = (const float*)d_in[15];
  const float* fc1_b     = (const float*)d_in[16];
  const float* fc2_w     = (const float*)d_in[17];
  const float* fc2_b     = (const float*)d_in[18];
  const float* gamma2    = (const float*)d_in[19];
  const float* fcn_g     = (const float*)d_in[20];
  const float* fcn_b     = (const float*)d_in[21];
  const int* rel_index   = (const int*)d_in[22];
  float* out = (float*)d_out;

  char* ws = (char*)d_ws;
  size_t off = 0;
  auto take = [&](size_t bytes) {
    char* p = ws + off;
    off += (bytes + 255) & ~(size_t)255;
    return p;
  };
  unsigned short* wl     = (unsigned short*)take((size_t)WL_ELEMS * 2);
  unsigned short* pwb    = (unsigned short*)take((size_t)589824 * 2);
  float*          tokf   = (float*)take((size_t)MPAD * 768 * 4);
  unsigned short* hb     = (unsigned short*)take((size_t)MPAD * 768 * 2);
  unsigned short* qkvb   = (unsigned short*)take((size_t)MPAD * 2304 * 2);
  unsigned short* ffb    = (unsigned short*)take((size_t)MPAD * 3072 * 2);
  unsigned short* rpbAll = (unsigned short*)take((size_t)RPB_PER_L * NLAYER * 2);
  unsigned short* xp = ffb;
  unsigned short* ob = hb;
  unsigned short* wl_qkv = wl;
  unsigned short* wl_proj = wl + (size_t)2304 * 768;
  unsigned short* wl_fc1 = wl_proj + (size_t)768 * 768;
  unsigned short* wl_fc2 = wl_fc1 + (size_t)3072 * 768;

  // one-time: rel-pos bias expansion
  build_rpb<<<(RPB_PER_L * NLAYER + 255) / 256, 256, 0, stream>>>(rel_table, rel_index, rpbAll);

  // patch embed
  cvt4<<<576, 256, 0, stream>>>((const float4*)patch_w, (ushort4*)pwb, 147456);
  build_xp<<<18816, 256, 0, stream>>>(x, xp);
  gemm_t<0, 64><<<dim3(6, 100), 256, 0, stream>>>(xp, pwb, tokf, nullptr, patch_b,
                                                  nullptr, nullptr, 768, 768);
  fill_cls<<<96, 256, 0, stream>>>(cls_tok, tokf);

  for (int l = 0; l < NLAYER; ++l) {
    cvt_layer<<<(WL_ELEMS / 4 + 255) / 256, 256, 0, stream>>>(
        (const float4*)(qkv_w + (size_t)l * 2304 * 768),
        (const float4*)(proj_w + (size_t)l * 768 * 768),
        (const float4*)(fc1_w + (size_t)l * 3072 * 768),
        (const float4*)(fc2_w + (size_t)l * 768 * 3072), (ushort4*)wl);
    ln_rows<<<MROWS, 256, 0, stream>>>(tokf, hb, ln1_g + l * 768, ln1_b + l * 768);
    gemm_t<1, 128><<<dim3(18, 50), 256, 0, stream>>>(hb, wl_qkv, nullptr, qkvb,
                                                     q_bias + l * 768, v_bias + l * 768,
                                                     nullptr, 768, 2304);
    attn_mfma<<<384, 256, 0, stream>>>(qkvb, rpbAll + (size_t)l * RPB_PER_L, ob);
    gemm_t<2, 64><<<dim3(6, 100), 256, 0, stream>>>(ob, wl_proj, tokf, nullptr,
                                                    proj_b + l * 768, nullptr,
                                                    gamma1 + l * 768, 768, 768);
    ln_rows<<<MROWS, 256, 0, stream>>>(tokf, hb, ln2_g + l * 768, ln2_b + l * 768);
    gemm_t<3, 128><<<dim3(24, 50), 256, 0, stream>>>(hb, wl_fc1, nullptr, ffb,
                                                     fc1_b + l * 3072, nullptr, nullptr,
                                                     768, 3072);
    gemm_t<2, 64><<<dim3(6, 100), 256, 0, stream>>>(ffb, wl_fc2, tokf, nullptr,
                                                    fc2_b + l * 768, nullptr,
                                                    gamma2 + l * 768, 3072, 768);
  }
  pool_ln<<<32, 256, 0, stream>>>(tokf, fcn_g, fcn_b, out);
}